// Round 1
// baseline (1642.099 us; speedup 1.0000x reference)
//
#include <hip/hip_runtime.h>
#include <math.h>

// Problem constants (from reference)
constexpr int B    = 512;
constexpr int NPG  = 200;    // nodes per graph, stage 0
constexpr int EPER = 2000;   // edges per graph
constexpr int EMB  = 9;
constexpr int HID  = 128;
constexpr int K1   = 160;    // ceil(0.8*200)
constexpr int K2   = 128;    // ceil(0.8*160)
constexpr int K3   = 103;    // ceil(0.8*128)
constexpr int N0   = B * NPG;   // 102400
constexpr int N1   = B * K1;    // 81920
constexpr int N2   = B * K2;    // 65536
constexpr int N3   = B * K3;    // 52736
constexpr int E    = B * EPER;  // 1024000

// ---------------------------------------------------------------------------
// Embedding gather: x0[n][:] = emb[node_ids[n]][:]
__global__ void k_gather(const int* __restrict__ node_ids,
                         const float* __restrict__ emb,
                         float* __restrict__ x0) {
    int n = blockIdx.x * blockDim.x + threadIdx.x;
    if (n < N0) {
        int id = node_ids[n];
        #pragma unroll
        for (int j = 0; j < EMB; j++) x0[n * EMB + j] = emb[id * EMB + j];
    }
}

// ---------------------------------------------------------------------------
// Stage-1 aggregation (width EMB=9), all edges valid. One block per graph,
// accumulate in LDS (per-graph node range is contiguous).
__global__ void k_agg9(const float* __restrict__ x0,
                       const int* __restrict__ esrc,
                       const int* __restrict__ edst,
                       float* __restrict__ s9,
                       float* __restrict__ cnt) {
    int g = blockIdx.x;
    __shared__ float lacc[NPG * EMB];
    __shared__ float lcnt[NPG];
    for (int i = threadIdx.x; i < NPG * EMB; i += 256) lacc[i] = 0.f;
    for (int i = threadIdx.x; i < NPG; i += 256) lcnt[i] = 0.f;
    __syncthreads();
    const int ebase = g * EPER;
    const int nbase = g * NPG;
    for (int idx = threadIdx.x; idx < EPER * EMB; idx += 256) {
        int el = idx / EMB;
        int j  = idx - el * EMB;
        int e  = ebase + el;
        int src = esrc[e];
        int dl  = edst[e] - nbase;
        atomicAdd(&lacc[dl * EMB + j], x0[src * EMB + j]);
        if (j == 0) atomicAdd(&lcnt[dl], 1.f);
    }
    __syncthreads();
    for (int i = threadIdx.x; i < NPG * EMB; i += 256) s9[nbase * EMB + i] = lacc[i];
    for (int i = threadIdx.x; i < NPG; i += 256) cnt[nbase + i] = lcnt[i];
}

// ---------------------------------------------------------------------------
// Stage-2/3 aggregation (width 128). Feature dim split over blockIdx.y (2
// halves of 64) to keep LDS under 64 KB: LDS = npc*64*4 + npc*4 bytes.
__global__ void k_agg128(const float* __restrict__ x,
                         const int* __restrict__ esrc,
                         const int* __restrict__ edst,
                         const int* __restrict__ evalid,
                         int npc,
                         float* __restrict__ s,
                         float* __restrict__ cnt) {
    int g = blockIdx.x;
    int w = blockIdx.y;   // which half of the feature dim
    extern __shared__ float lds[];
    float* lacc = lds;            // npc * 64
    float* lcnt = lds + npc * 64; // npc (only meaningful for w==0)
    int tot = npc * 64 + npc;
    for (int i = threadIdx.x; i < tot; i += 256) lds[i] = 0.f;
    __syncthreads();
    const int ebase = g * EPER;
    const int nbase = g * npc;
    const int hoff  = w * 64;
    for (int idx = threadIdx.x; idx < EPER * 64; idx += 256) {
        int el = idx >> 6;
        int hh = idx & 63;
        int e  = ebase + el;
        if (evalid[e]) {
            int src = esrc[e];
            int dl  = edst[e] - nbase;
            atomicAdd(&lacc[dl * 64 + hh], x[(long)src * HID + hoff + hh]);
            if (hh == 0 && w == 0) atomicAdd(&lcnt[dl], 1.f);
        }
    }
    __syncthreads();
    for (int i = threadIdx.x; i < npc * 64; i += 256) {
        int l = i >> 6, hh = i & 63;
        s[(long)(nbase + l) * HID + hoff + hh] = lacc[i];
    }
    if (w == 0)
        for (int i = threadIdx.x; i < npc; i += 256) cnt[nbase + i] = lcnt[i];
}

// ---------------------------------------------------------------------------
// Conv1: out[n][h] = relu( mean9[n] . w1n[h] + x0[n] . w1r[h] + b[h] )
// NB nodes per block, 128 threads (one per output feature).
template <int NB>
__global__ void k_conv1(const float* __restrict__ s9,
                        const float* __restrict__ cnt,
                        const float* __restrict__ x0,
                        const float* __restrict__ wn,
                        const float* __restrict__ wr,
                        const float* __restrict__ bb,
                        float* __restrict__ out) {
    __shared__ float sm[NB][EMB];
    __shared__ float sx[NB][EMB];
    int nb0 = blockIdx.x * NB;
    int h = threadIdx.x;  // 128
    for (int i = h; i < NB * EMB; i += 128) {
        int sl = i / EMB, j = i - sl * EMB;
        int n = nb0 + sl;
        float invc = 1.f / fmaxf(cnt[n], 1.f);
        sm[sl][j] = s9[n * EMB + j] * invc;
        sx[sl][j] = x0[n * EMB + j];
    }
    __syncthreads();
    float acc[NB];
    #pragma unroll
    for (int sl = 0; sl < NB; sl++) acc[sl] = bb[h];
    #pragma unroll
    for (int j = 0; j < EMB; j++) {
        float a = wn[h * EMB + j];
        float r = wr[h * EMB + j];
        #pragma unroll
        for (int sl = 0; sl < NB; sl++) acc[sl] += sm[sl][j] * a + sx[sl][j] * r;
    }
    #pragma unroll
    for (int sl = 0; sl < NB; sl++)
        out[(long)(nb0 + sl) * HID + h] = fmaxf(acc[sl], 0.f);
}

// ---------------------------------------------------------------------------
// Conv2/3: out[n][h] = relu( (s[n]/max(cnt,1)) . wn[h] + xin[n] . wr[h] + b[h] )
// May be called with out == s (in-place): all reads of s happen before the
// barrier, all writes after, and blocks touch disjoint node ranges.
template <int NB>
__global__ void k_conv128(const float* s,               // no restrict: may alias out
                          const float* __restrict__ cnt,
                          const float* __restrict__ xin,
                          const float* __restrict__ wn,
                          const float* __restrict__ wr,
                          const float* __restrict__ bb,
                          float* out) {
    __shared__ float sm[NB][HID];
    __shared__ float sx[NB][HID];
    int nb0 = blockIdx.x * NB;
    int h = threadIdx.x;  // 128
    for (int i = h; i < NB * HID; i += 128) {
        int sl = i >> 7, j = i & 127;
        int n = nb0 + sl;
        float invc = 1.f / fmaxf(cnt[n], 1.f);
        sm[sl][j] = s[(long)n * HID + j] * invc;
        sx[sl][j] = xin[(long)n * HID + j];
    }
    __syncthreads();
    float acc[NB];
    #pragma unroll
    for (int sl = 0; sl < NB; sl++) acc[sl] = bb[h];
    #pragma unroll 4
    for (int j = 0; j < HID; j++) {
        float a = wn[h * HID + j];
        float r = wr[h * HID + j];
        #pragma unroll
        for (int sl = 0; sl < NB; sl++) acc[sl] += sm[sl][j] * a + sx[sl][j] * r;
    }
    #pragma unroll
    for (int sl = 0; sl < NB; sl++)
        out[(long)(nb0 + sl) * HID + h] = fmaxf(acc[sl], 0.f);
}

// ---------------------------------------------------------------------------
// TopK pool: score = tanh(x.p/||p||); select top-k per graph with
// jax.lax.top_k semantics (descending, lower index wins ties); write
// xout[g*k+rank] = x[node]*score and mapping (old global id -> new or -1).
__global__ void k_pool(const float* __restrict__ x,
                       const float* __restrict__ p,
                       int npc, int k,
                       float* __restrict__ xout,
                       int* __restrict__ mapping) {
    int g = blockIdx.x;
    int tid = threadIdx.x;  // 256
    __shared__ float sc[256];
    __shared__ int   pos[256];
    __shared__ float red[256];
    // ||p||
    float v = 0.f;
    if (tid < HID) { float t = p[tid]; v = t * t; }
    red[tid] = v;
    __syncthreads();
    for (int off = 128; off >= 1; off >>= 1) {
        if (tid < off) red[tid] += red[tid + off];
        __syncthreads();
    }
    float nrm = sqrtf(red[0]);
    // scores
    float scv = 0.f;
    if (tid < npc) {
        const float* xr = x + (long)(g * npc + tid) * HID;
        float d = 0.f;
        #pragma unroll 4
        for (int j = 0; j < HID; j++) d += xr[j] * p[j];
        scv = tanhf(d / nrm);
        sc[tid] = scv;
    }
    __syncthreads();
    // rank = position in descending stable order
    if (tid < npc) {
        int rank = 0;
        for (int j = 0; j < npc; j++) {
            float o = sc[j];
            rank += (o > scv) || (o == scv && j < tid);
        }
        bool keep = rank < k;
        pos[tid] = keep ? rank : -1;
        mapping[g * npc + tid] = keep ? (g * k + rank) : -1;
    }
    __syncthreads();
    // gather + scale into new ordering
    for (int idx = tid; idx < npc * HID; idx += 256) {
        int i = idx >> 7, h = idx & 127;
        int r = pos[i];
        if (r >= 0)
            xout[(long)(g * k + r) * HID + h] = x[(long)(g * npc + i) * HID + h] * sc[i];
    }
}

// ---------------------------------------------------------------------------
// Edge remap after pooling. May run in-place (sin==sout etc): each thread
// reads then writes only its own slot.
__global__ void k_edgeupd(const int* sin, const int* din, const int* vin,
                          const int* __restrict__ mapping,
                          int* sout, int* dout, int* vout) {
    int e = blockIdx.x * blockDim.x + threadIdx.x;
    if (e < E) {
        int v  = vin ? vin[e] : 1;
        int ns = mapping[sin[e]];
        int nd = mapping[din[e]];
        int nv = (v && ns >= 0 && nd >= 0) ? 1 : 0;
        sout[e] = ns >= 0 ? ns : 0;
        dout[e] = nd >= 0 ? nd : 0;
        vout[e] = nv;
    }
}

// ---------------------------------------------------------------------------
// Global pool: gout[g][0:128]=max over k rows, gout[g][128:256]=mean.
__global__ void k_gpool(const float* __restrict__ x, int k,
                        float* __restrict__ gout) {
    int g = blockIdx.x, h = threadIdx.x;  // 128 threads
    float mx = -INFINITY, sm = 0.f;
    for (int i = 0; i < k; i++) {
        float v = x[(long)(g * k + i) * HID + h];
        mx = fmaxf(mx, v);
        sm += v;
    }
    gout[g * 256 + h] = mx;
    gout[g * 256 + 128 + h] = sm / (float)k;
}

// ---------------------------------------------------------------------------
// MLP head: h=g1+g2+g3; relu(h@lw1.T+lb1); relu(@lw2.T+lb2); sigmoid(@lw3.T+lb3)
__global__ void k_mlp(const float* __restrict__ g1, const float* __restrict__ g2,
                      const float* __restrict__ g3,
                      const float* __restrict__ lw1, const float* __restrict__ lb1,
                      const float* __restrict__ lw2, const float* __restrict__ lb2,
                      const float* __restrict__ lw3, const float* __restrict__ lb3,
                      float* __restrict__ out) {
    int g = blockIdx.x, t = threadIdx.x;  // 128 threads
    __shared__ float h0[256];
    __shared__ float h1[128];
    __shared__ float h2r[64];
    h0[t]       = g1[g * 256 + t] + g2[g * 256 + t] + g3[g * 256 + t];
    h0[t + 128] = g1[g * 256 + 128 + t] + g2[g * 256 + 128 + t] + g3[g * 256 + 128 + t];
    __syncthreads();
    float a = lb1[t];
    #pragma unroll 4
    for (int j = 0; j < 256; j++) a += h0[j] * lw1[t * 256 + j];
    h1[t] = fmaxf(a, 0.f);
    __syncthreads();
    if (t < 64) {
        float a2 = lb2[t];
        #pragma unroll 4
        for (int j = 0; j < 128; j++) a2 += h1[j] * lw2[t * 128 + j];
        h2r[t] = fmaxf(a2, 0.f) * lw3[t];
    }
    __syncthreads();
    if (t == 0) {
        float s = 0.f;
        for (int j = 0; j < 64; j++) s += h2r[j];
        s += lb3[0];
        out[g] = 1.f / (1.f + expf(-s));
    }
}

// ---------------------------------------------------------------------------
extern "C" void kernel_launch(void* const* d_in, const int* in_sizes, int n_in,
                              void* d_out, int out_size, void* d_ws, size_t ws_size,
                              hipStream_t stream) {
    const int*   node_ids = (const int*)d_in[0];
    const int*   ei   = (const int*)d_in[1];   // edge_index (2, E)
    const float* emb  = (const float*)d_in[3];
    const float* w1n  = (const float*)d_in[4];
    const float* w1r  = (const float*)d_in[5];
    const float* b1   = (const float*)d_in[6];
    const float* w2n  = (const float*)d_in[7];
    const float* w2r  = (const float*)d_in[8];
    const float* b2   = (const float*)d_in[9];
    const float* w3n  = (const float*)d_in[10];
    const float* w3r  = (const float*)d_in[11];
    const float* b3   = (const float*)d_in[12];
    const float* p1   = (const float*)d_in[13];
    const float* p2   = (const float*)d_in[14];
    const float* p3   = (const float*)d_in[15];
    const float* lw1  = (const float*)d_in[16];
    const float* lb1  = (const float*)d_in[17];
    const float* lw2  = (const float*)d_in[18];
    const float* lb2  = (const float*)d_in[19];
    const float* lw3  = (const float*)d_in[20];
    const float* lb3  = (const float*)d_in[21];
    float* out = (float*)d_out;

    // Workspace layout (floats). x0/s9 alias the front of D (dead before
    // D's first real use as pool-1 output).
    float* ws  = (float*)d_ws;
    float* C   = ws;                           // N0*HID   (x1 / s-acc / x2 / s3 / x3)
    float* D   = C + (size_t)N0 * HID;         // N1*HID   (x1p / x2p / x3p)
    float* x0  = D;                            // N0*EMB   (stage 1 only)
    float* s9  = D + (size_t)N0 * EMB;         // N0*EMB   (stage 1 only)
    float* cnt = D + (size_t)N1 * HID;         // N0
    float* g1  = cnt + N0;                     // B*256
    float* g2  = g1 + B * 2 * HID;             // B*256
    float* g3  = g2 + B * 2 * HID;             // B*256
    int* mapping = (int*)(g3 + B * 2 * HID);   // N0
    int* esrc  = mapping + N0;                 // E
    int* edst  = esrc + E;                     // E
    int* evalid = edst + E;                    // E

    // ---- Stage 1 (EMB -> HID) ----
    k_gather<<<(N0 + 255) / 256, 256, 0, stream>>>(node_ids, emb, x0);
    k_agg9<<<B, 256, 0, stream>>>(x0, ei, ei + E, s9, cnt);
    k_conv1<8><<<N0 / 8, 128, 0, stream>>>(s9, cnt, x0, w1n, w1r, b1, C);
    k_pool<<<B, 256, 0, stream>>>(C, p1, NPG, K1, D, mapping);
    k_edgeupd<<<(E + 255) / 256, 256, 0, stream>>>(ei, ei + E, nullptr, mapping,
                                                   esrc, edst, evalid);
    k_gpool<<<B, 128, 0, stream>>>(D, K1, g1);

    // ---- Stage 2 (HID -> HID), nodes N1 ----
    {
        size_t sh = (size_t)(K1 * 64 + K1) * sizeof(float);
        k_agg128<<<dim3(B, 2), 256, sh, stream>>>(D, esrc, edst, evalid, K1, C, cnt);
    }
    k_conv128<8><<<N1 / 8, 128, 0, stream>>>(C, cnt, D, w2n, w2r, b2, C);
    k_pool<<<B, 256, 0, stream>>>(C, p2, K1, K2, D, mapping);
    k_edgeupd<<<(E + 255) / 256, 256, 0, stream>>>(esrc, edst, evalid, mapping,
                                                   esrc, edst, evalid);
    k_gpool<<<B, 128, 0, stream>>>(D, K2, g2);

    // ---- Stage 3 (HID -> HID), nodes N2 ----
    {
        size_t sh = (size_t)(K2 * 64 + K2) * sizeof(float);
        k_agg128<<<dim3(B, 2), 256, sh, stream>>>(D, esrc, edst, evalid, K2, C, cnt);
    }
    k_conv128<8><<<N2 / 8, 128, 0, stream>>>(C, cnt, D, w3n, w3r, b3, C);
    k_pool<<<B, 256, 0, stream>>>(C, p3, K2, K3, D, mapping);
    // (final edge update is unused by the reference output -> skipped)
    k_gpool<<<B, 128, 0, stream>>>(D, K3, g3);

    // ---- Head ----
    k_mlp<<<B, 128, 0, stream>>>(g1, g2, g3, lw1, lb1, lw2, lb2, lw3, lb3, out);
}